// Round 10
// baseline (1348.084 us; speedup 1.0000x reference)
//
#include <hip/hip_runtime.h>
#include <hip/hip_bf16.h>
#include <hip/hip_fp16.h>
#include <math.h>

// ---------------------------------------------------------------------------
// GATGNN forward. fp32 math + fp32 LDS tiles (r8 core, zero-spill, proven);
// ea / M(tj) HBM streams fp16 (~132 MB ws).
//   h = x@Wn + bn; ea = leaky_relu(eattr@We + be)        [ea fp16 in HBM]
//   CSR build once per launch (graph static across layers).
//   per layer:
//     P = h@Wtop                          (fp32 register-tiled GEMM)
//     fused: M = ea@Wbot; ti=sp(P[dst]+M), tj=sp(P[src]+M); M<-tj (fp16);
//            a1 = sp(dot(ti,att_i)+dot(tj,att_j)); a1 stats via atomics
//     aggregate (CSR gather, NO atomics): per dst node, walk edge list,
//            ew = exp(sp(BN(a1))) inline; aggn = (sum tj*ew)/(sum ew);
//            col stats block-reduced into cs
//     h = sp(BN(aggn))                    (conv_bias cancels in BN)
//   comp attention + seg-softmax over sorted batch + pool + fc
// Lessons pinned:
//  - NEVER pass min-waves to __launch_bounds__ (r6/r7: VGPR cap -> GBs spill).
//  - r9: dot2 reg-tiles (VGPR 144) killed occupancy 33%->10% -> slower.
//    Keep the 52-VGPR fp32-LDS MAC loop.
//  - r8 edgeB was atomic-bound (25.6M fp32 atomics) -> CSR gather instead.
// ---------------------------------------------------------------------------

typedef unsigned short ushortt;

__device__ __forceinline__ float sp_f(float x) {
  return x > 20.0f ? x : __logf(1.0f + __expf(x));
}
__device__ __forceinline__ float h2f(ushortt u) {
  union { ushortt u; __half h; } c; c.u = u;
  return __half2float(c.h);
}
__device__ __forceinline__ ushortt f2h(float f) {
  union { __half h; ushortt u; } c; c.h = __float2half(f);
  return c.u;
}
__device__ __forceinline__ float4 h4_to_f4(ushort4 u) {
  return make_float4(h2f(u.x), h2f(u.y), h2f(u.z), h2f(u.w));
}

// Register-tiled GEMM: out[R,64] = act(in[R,K] @ W[K,64] (+ b))
// Block: 256 thr, tile 64 rows x 64 cols; thread: 4 rows x 4 cols.
// LDS tiles ALWAYS fp32 (r8 core). FP16IN: global `in` is fp16, converted
// during LDS staging. FUSE_A: epilogue gathers P[dst],P[src], writes tj
// (fp16) over out, emits a1 + accumulates a1 sum/sumsq into stats[0..1].
template<int K, int ACT, int BIAS, int FUSE_A, int FP16IN, typename IT, typename OT>
__global__ __launch_bounds__(256) void k_gemm_rt(
    const IT* __restrict__ in, const float* __restrict__ W,
    const float* __restrict__ b, OT* __restrict__ out, int R,
    const float* __restrict__ P, const int* __restrict__ eidx,
    const float* __restrict__ catt, float* __restrict__ a1,
    float* __restrict__ stats)
{
  constexpr int KP = (K + 3) / 4 * 4;   // k padded to x4 (zero-filled)
  constexpr int LS = KP + 4;            // ins row stride (floats, 16B-aligned)
  __shared__ __align__(16) float ins[64 * LS];
  __shared__ __align__(16) float Ws[KP * 64];
  __shared__ float atts[128];
  __shared__ float ssum[4], ssq[4];

  const int tx = threadIdx.x;
  const int b0 = blockIdx.x * 64;

  for (int i = tx; i < KP * 64; i += 256) {
    const int k = i >> 6;
    Ws[i] = (k < K) ? W[i] : 0.0f;      // W row-major [K][64]; pad rows zero
  }
  if (FP16IN) {
    static_assert(!FP16IN || (K % 8 == 0), "fp16 staging needs K%8==0");
    for (int i = tx; i < 64 * (K / 8); i += 256) {
      const int row = i / (K / 8);
      const int k8 = i % (K / 8);
      long r = b0 + row; if (r >= R) r = R - 1;   // clamp: values unused
      const ushortt* sp = &((const ushortt*)in)[r * (long)K + k8 * 8];
      const ushort4 u0 = *(const ushort4*)sp;
      const ushort4 u1 = *(const ushort4*)(sp + 4);
      *(float4*)&ins[row * LS + k8 * 8]     = h4_to_f4(u0);
      *(float4*)&ins[row * LS + k8 * 8 + 4] = h4_to_f4(u1);
    }
  } else {
    for (int i = tx; i < 64 * (KP / 4); i += 256) {
      const int row = i / (KP / 4);
      const int k4 = i % (KP / 4);
      long r = b0 + row; if (r >= R) r = R - 1;   // clamp: values unused
      float4 v;
      if (K % 4 == 0) {
        v = *(const float4*)&((const float*)in)[r * (long)K + k4 * 4];
      } else {
        float t[4];
        #pragma unroll
        for (int j = 0; j < 4; ++j) {
          const int k = k4 * 4 + j;
          t[j] = (k < K) ? ((const float*)in)[r * (long)K + k] : 0.0f;
        }
        v = make_float4(t[0], t[1], t[2], t[3]);
      }
      *(float4*)&ins[row * LS + k4 * 4] = v;
    }
  }
  if (FUSE_A) { if (tx < 128) atts[tx] = catt[tx]; }
  __syncthreads();

  const int lr0 = ((tx >> 6) << 4) + (((tx >> 4) & 3) << 2);  // local row base
  const int c0 = (tx & 15) << 2;                               // col base
  float acc[4][4];
  #pragma unroll
  for (int i = 0; i < 4; ++i)
    #pragma unroll
    for (int j = 0; j < 4; ++j) acc[i][j] = 0.0f;

  #pragma unroll 4
  for (int k4 = 0; k4 < KP / 4; ++k4) {
    float4 w[4], a[4];
    #pragma unroll
    for (int kk = 0; kk < 4; ++kk)
      w[kk] = *(const float4*)&Ws[(k4 * 4 + kk) * 64 + c0];
    #pragma unroll
    for (int ri = 0; ri < 4; ++ri)
      a[ri] = *(const float4*)&ins[(lr0 + ri) * LS + k4 * 4];
    #pragma unroll
    for (int ri = 0; ri < 4; ++ri) {
      const float* av = (const float*)&a[ri];
      #pragma unroll
      for (int kk = 0; kk < 4; ++kk) {
        acc[ri][0] = fmaf(av[kk], w[kk].x, acc[ri][0]);
        acc[ri][1] = fmaf(av[kk], w[kk].y, acc[ri][1]);
        acc[ri][2] = fmaf(av[kk], w[kk].z, acc[ri][2]);
        acc[ri][3] = fmaf(av[kk], w[kk].w, acc[ri][3]);
      }
    }
  }

  if (!FUSE_A) {
    float4 bias = make_float4(0.f, 0.f, 0.f, 0.f);
    if (BIAS) bias = *(const float4*)&b[c0];
    #pragma unroll
    for (int ri = 0; ri < 4; ++ri) {
      const long r = b0 + lr0 + ri;
      if (r >= R) continue;
      float4 v;
      v.x = acc[ri][0] + bias.x; v.y = acc[ri][1] + bias.y;
      v.z = acc[ri][2] + bias.z; v.w = acc[ri][3] + bias.w;
      if (ACT == 1) {
        v.x = v.x >= 0.f ? v.x : 0.2f * v.x;  v.y = v.y >= 0.f ? v.y : 0.2f * v.y;
        v.z = v.z >= 0.f ? v.z : 0.2f * v.z;  v.w = v.w >= 0.f ? v.w : 0.2f * v.w;
      }
      if (sizeof(OT) == 4) {
        *(float4*)&out[r * 64 + c0] = v;
      } else {
        ushort4 u;
        u.x = f2h(v.x); u.y = f2h(v.y); u.z = f2h(v.z); u.w = f2h(v.w);
        *(ushort4*)&out[r * 64 + c0] = u;
      }
    }
  } else {
    // epilogue: ti/tj, write tj (fp16) over out, attention logit a1, a1 stats
    float s1 = 0.f, s2 = 0.f;
    #pragma unroll
    for (int ri = 0; ri < 4; ++ri) {
      const long e = b0 + lr0 + ri;
      float part = 0.0f;
      if (e < R) {
        const int s = eidx[e];
        const int d = eidx[(long)R + e];
        const float4 Pd = *(const float4*)&P[(long)d * 64 + c0];
        const float4 Ps = *(const float4*)&P[(long)s * 64 + c0];
        float tj[4];
        const float ti0 = sp_f(Pd.x + acc[ri][0]);
        const float ti1 = sp_f(Pd.y + acc[ri][1]);
        const float ti2 = sp_f(Pd.z + acc[ri][2]);
        const float ti3 = sp_f(Pd.w + acc[ri][3]);
        tj[0] = sp_f(Ps.x + acc[ri][0]);
        tj[1] = sp_f(Ps.y + acc[ri][1]);
        tj[2] = sp_f(Ps.z + acc[ri][2]);
        tj[3] = sp_f(Ps.w + acc[ri][3]);
        ushort4 u;
        u.x = f2h(tj[0]); u.y = f2h(tj[1]); u.z = f2h(tj[2]); u.w = f2h(tj[3]);
        *(ushort4*)&out[e * 64 + c0] = u;
        part = ti0 * atts[c0] + ti1 * atts[c0 + 1] + ti2 * atts[c0 + 2] + ti3 * atts[c0 + 3]
             + tj[0] * atts[64 + c0] + tj[1] * atts[64 + c0 + 1]
             + tj[2] * atts[64 + c0 + 2] + tj[3] * atts[64 + c0 + 3];
      }
      #pragma unroll
      for (int off = 8; off; off >>= 1) part += __shfl_xor(part, off);
      if ((tx & 15) == 0 && e < R) {
        const float v = sp_f(part);
        a1[e] = v;
        s1 += v; s2 += v * v;
      }
    }
    s1 += __shfl_xor(s1, 16); s2 += __shfl_xor(s2, 16);
    s1 += __shfl_xor(s1, 32); s2 += __shfl_xor(s2, 32);
    if ((tx & 63) == 0) { ssum[tx >> 6] = s1; ssq[tx >> 6] = s2; }
    __syncthreads();
    if (tx == 0) {
      atomicAdd(&stats[0], ssum[0] + ssum[1] + ssum[2] + ssum[3]);
      atomicAdd(&stats[1], ssq[0] + ssq[1] + ssq[2] + ssq[3]);
    }
  }
}

// ---------- CSR build (once per launch; graph static across layers) --------
__global__ __launch_bounds__(256) void k_count(
    const int* __restrict__ dst, int* __restrict__ counts, int E)
{
  for (int i = blockIdx.x * 256 + threadIdx.x; i < E; i += gridDim.x * 256)
    atomicAdd(&counts[dst[i]], 1);
}

// single-block exclusive scan: offs[0..N-1] = exclusive prefix, offs[N] = E
__global__ __launch_bounds__(1024) void k_scan(
    const int* __restrict__ counts, int* __restrict__ offs, int N)
{
  __shared__ int part[1024];
  const int t = threadIdx.x;
  const int chunk = (N + 1023) >> 10;
  const int s0 = t * chunk;
  int sum = 0;
  for (int i = 0; i < chunk; ++i) {
    const int idx = s0 + i;
    if (idx < N) sum += counts[idx];
  }
  part[t] = sum;
  __syncthreads();
  for (int off = 1; off < 1024; off <<= 1) {
    const int v = (t >= off) ? part[t - off] : 0;
    __syncthreads();
    part[t] += v;
    __syncthreads();
  }
  int base = (t == 0) ? 0 : part[t - 1];
  for (int i = 0; i < chunk; ++i) {
    const int idx = s0 + i;
    if (idx < N) { offs[idx] = base; base += counts[idx]; }
  }
  if (N - 1 >= s0 && N - 1 < s0 + chunk) offs[N] = base;
}

__global__ __launch_bounds__(256) void k_fill(
    const int* __restrict__ dst, const int* __restrict__ offs,
    int* __restrict__ cursors, int* __restrict__ eids, int E)
{
  for (int i = blockIdx.x * 256 + threadIdx.x; i < E; i += gridDim.x * 256) {
    const int d = dst[i];
    const int pos = offs[d] + atomicAdd(&cursors[d], 1);
    eids[pos] = i;
  }
}

// ---------- aggregate: CSR gather, no atomics on agg ------------------------
// one wave per dst node: ew = exp(sp(BN(a1[e]))) inline;
// aggn[n] = (sum_e tj[e]*ew)/(sum_e ew); col sum/sumsq block-reduced into cs.
__global__ __launch_bounds__(256) void k_aggregate(
    const int* __restrict__ offs, const int* __restrict__ eids,
    const float* __restrict__ a1, const ushortt* __restrict__ M,
    const float* __restrict__ stats, float invE,
    float* __restrict__ aggn, float* __restrict__ cs, int N)
{
  const float mean = stats[0] * invE;
  const float var = stats[1] * invE - mean * mean;
  const float scl = rsqrtf(var + 1e-5f);
  const int t = threadIdx.x & 63;
  const int wid = threadIdx.x >> 6;
  float s = 0.f, s2 = 0.f;
  const long step = (long)gridDim.x * 4;
  for (long n = (long)blockIdx.x * 4 + wid; n < N; n += step) {
    const int o0 = offs[n];
    const int o1 = offs[n + 1];
    float av = 0.f, sew = 0.f;
    for (int i = o0; i < o1; ++i) {
      const int e = eids[i];
      const float w = __expf(sp_f((a1[e] - mean) * scl));
      av = fmaf(h2f(M[(long)e * 64 + t]), w, av);
      sew += w;
    }
    const float v = (o1 > o0) ? av / sew : 0.0f;
    aggn[n * 64 + t] = v;
    s += v; s2 += v * v;
  }
  __shared__ float b1[256], b2[256];
  b1[threadIdx.x] = s; b2[threadIdx.x] = s2;
  __syncthreads();
  if (threadIdx.x < 64) {
    atomicAdd(&cs[t], b1[t] + b1[64 + t] + b1[128 + t] + b1[192 + t]);
    atomicAdd(&cs[64 + t], b2[t] + b2[64 + t] + b2[128 + t] + b2[192 + t]);
  }
}

// h = sp((aggn - mean_c) * rsqrt(var_c + eps))
__global__ __launch_bounds__(256) void k_hnew(
    const float* __restrict__ aggn, const float* __restrict__ cs,
    float invN, float* __restrict__ h, int N)
{
  const int c = threadIdx.x & 63;
  const int r = threadIdx.x >> 6;
  const float mean = cs[c] * invN;
  const float var = cs[64 + c] * invN - mean * mean;
  const float scl = rsqrtf(var + 1e-5f);
  for (long n = (long)blockIdx.x * 4 + r; n < N; n += (long)gridDim.x * 4)
    h[n * 64 + c] = sp_f((aggn[n * 64 + c] - mean) * scl);
}

// composition attention score a[n] = sp(concat(h,gf)@Wc + bc) @ attW + attb
__global__ __launch_bounds__(256) void k_comp(
    const float* __restrict__ h, const float* __restrict__ gf,
    const int* __restrict__ batch, const float* __restrict__ Wc,
    const float* __restrict__ bc, const float* __restrict__ aw,
    const float* __restrict__ ab, float* __restrict__ aN, int N)
{
  __shared__ float Wcs[167 * 32];
  __shared__ float aws[32];
  __shared__ float bcs[32];
  for (int i = threadIdx.x; i < 167 * 32; i += 256) Wcs[i] = Wc[i];
  if (threadIdx.x < 32) { aws[threadIdx.x] = aw[threadIdx.x]; bcs[threadIdx.x] = bc[threadIdx.x]; }
  __syncthreads();
  const int t = threadIdx.x & 63;
  const int wid = threadIdx.x >> 6;
  const int col = t & 31;
  const float ab0 = ab[0];
  const int step = gridDim.x * 4;
  for (int n = blockIdx.x * 4 + wid; n < N; n += step) {
    const int g = batch[n];
    const float hq = h[(long)n * 64 + t];
    const float g1 = gf[(long)g * 103 + t];
    const float g2 = (t < 39) ? gf[(long)g * 103 + 64 + t] : 0.f;
    float acc = bcs[col];
    #pragma unroll 8
    for (int k = 0; k < 64; ++k) acc = fmaf(__shfl(hq, k), Wcs[k * 32 + col], acc);
    #pragma unroll 8
    for (int k = 0; k < 64; ++k) acc = fmaf(__shfl(g1, k), Wcs[(64 + k) * 32 + col], acc);
    #pragma unroll
    for (int k = 0; k < 39; ++k) acc = fmaf(__shfl(g2, k), Wcs[(128 + k) * 32 + col], acc);
    float val = sp_f(acc) * aws[col];
    #pragma unroll
    for (int off = 16; off; off >>= 1) val += __shfl_xor(val, off);
    if (t == 0) aN[n] = val + ab0;
  }
}

// one 64-thread block per graph: seg-softmax over sorted batch + pool + fc
__global__ __launch_bounds__(64) void k_pool(
    const float* __restrict__ h, const float* __restrict__ aN,
    const int* __restrict__ batch, const float* __restrict__ fcW,
    const float* __restrict__ fcb, float* __restrict__ out, int N, int G)
{
  const int g = blockIdx.x;
  const int t = threadIdx.x;
  int lo = 0, hi = N;
  while (lo < hi) { int mid = (lo + hi) >> 1; if (batch[mid] < g) lo = mid + 1; else hi = mid; }
  const int s = lo;
  hi = N;
  while (lo < hi) { int mid = (lo + hi) >> 1; if (batch[mid] < g + 1) lo = mid + 1; else hi = mid; }
  const int e2 = lo;
  if (s >= e2) { if (t == 0) out[g] = fcb[0]; return; }
  float mx = -1e30f;
  for (int i = s + t; i < e2; i += 64) mx = fmaxf(mx, aN[i]);
  #pragma unroll
  for (int off = 32; off; off >>= 1) mx = fmaxf(mx, __shfl_xor(mx, off));
  float se = 0.f;
  for (int i = s + t; i < e2; i += 64) se += __expf(aN[i] - mx);
  #pragma unroll
  for (int off = 32; off; off >>= 1) se += __shfl_xor(se, off);
  float acc = 0.f;
  for (int n = s; n < e2; ++n) {
    const float w = __expf(aN[n] - mx);
    acc = fmaf(h[(long)n * 64 + t], w, acc);
  }
  float part = (acc / se) * fcW[t];
  #pragma unroll
  for (int off = 32; off; off >>= 1) part += __shfl_xor(part, off);
  if (t == 0) out[g] = part + fcb[0];
}

extern "C" void kernel_launch(void* const* d_in, const int* in_sizes, int n_in,
                              void* d_out, int out_size, void* d_ws, size_t ws_size,
                              hipStream_t stream)
{
  const float* x     = (const float*)d_in[0];
  const int*   eidx  = (const int*)  d_in[1];
  const float* eattr = (const float*)d_in[2];
  const int*   batch = (const int*)  d_in[3];
  const float* gfeat = (const float*)d_in[4];
  const float* embnW = (const float*)d_in[5];
  const float* embnb = (const float*)d_in[6];
  const float* embeW = (const float*)d_in[7];
  const float* embeb = (const float*)d_in[8];
  const float* convW = (const float*)d_in[9];
  const float* convA = (const float*)d_in[10];
  // d_in[11] = conv_bias: cancels exactly in training-mode BatchNorm
  const float* compW = (const float*)d_in[12];
  const float* compb = (const float*)d_in[13];
  const float* attW  = (const float*)d_in[14];
  const float* attb  = (const float*)d_in[15];
  const float* fcW   = (const float*)d_in[16];
  const float* fcb   = (const float*)d_in[17];
  float* out = (float*)d_out;

  const int N = in_sizes[0] / 92;
  const int E = in_sizes[1] / 2;
  const int G = in_sizes[4] / 103;

  // workspace (~132 MB): fp32 node buffers, CSR ints, fp16 edge streams
  char* pw = (char*)d_ws;
  float* h     = (float*)pw;  pw += (size_t)N * 64 * 4;
  float* Pagg  = (float*)pw;  pw += (size_t)N * 64 * 4;   // P, then aggn
  float* aE    = (float*)pw;  pw += (size_t)E * 4;        // a1
  float* stats = (float*)pw;  pw += 256 * 4;              // [0..1] BN-E, [64..191] cs
  float* aN    = (float*)pw;  pw += (size_t)N * 4;
  int* counts  = (int*)pw;    pw += (size_t)N * 4;        // counts+cursors: one memset
  int* cursors = (int*)pw;    pw += (size_t)N * 4;
  int* offs    = (int*)pw;    pw += ((size_t)N + 1) * 4;
  int* eids    = (int*)pw;    pw += (size_t)E * 4;
  pw = (char*)(((size_t)pw + 63) & ~(size_t)63);
  ushortt* ea  = (ushortt*)pw; pw += (size_t)E * 64 * 2;  // fp16
  ushortt* M   = (ushortt*)pw;                            // fp16: M, then tj

  const int gE64 = (E + 63) / 64;
  const int gN64 = (N + 63) / 64;

  k_gemm_rt<92, 0, 1, 0, 0, float, float><<<gN64, 256, 0, stream>>>(
      x, embnW, embnb, h, N, nullptr, nullptr, nullptr, nullptr, nullptr);
  k_gemm_rt<41, 1, 1, 0, 0, float, ushortt><<<gE64, 256, 0, stream>>>(
      eattr, embeW, embeb, ea, E, nullptr, nullptr, nullptr, nullptr, nullptr);

  // CSR build (dst = eidx[E..2E))
  hipMemsetAsync(counts, 0, 2 * (size_t)N * sizeof(int), stream);
  k_count<<<2048, 256, 0, stream>>>(eidx + E, counts, E);
  k_scan<<<1, 1024, 0, stream>>>(counts, offs, N);
  k_fill<<<2048, 256, 0, stream>>>(eidx + E, offs, cursors, eids, E);

  for (int l = 0; l < 3; ++l) {
    const float* Wl = convW + (size_t)l * 128 * 64;
    const float* Al = convA + (size_t)l * 128;
    hipMemsetAsync(stats, 0, 256 * sizeof(float), stream);
    k_gemm_rt<64, 0, 0, 0, 0, float, float><<<gN64, 256, 0, stream>>>(
        h, Wl, nullptr, Pagg, N, nullptr, nullptr, nullptr, nullptr, nullptr);
    k_gemm_rt<64, 0, 0, 1, 1, ushortt, ushortt><<<gE64, 256, 0, stream>>>(
        ea, Wl + 64 * 64, nullptr, M, E, Pagg, eidx, Al, aE, stats);
    k_aggregate<<<4096, 256, 0, stream>>>(offs, eids, aE, M, stats,
                                          1.0f / (float)E, Pagg, stats + 64, N);
    k_hnew<<<2048, 256, 0, stream>>>(Pagg, stats + 64, 1.0f / (float)N, h, N);
  }

  k_comp<<<gN64, 256, 0, stream>>>(h, gfeat, batch, compW, compb, attW, attb, aN, N);
  k_pool<<<G, 64, 0, stream>>>(h, aN, batch, fcW, fcb, out, N, G);

  (void)n_in; (void)out_size; (void)ws_size;
}